// Round 2
// baseline (566.439 us; speedup 1.0000x reference)
//
#include <hip/hip_runtime.h>
#include <hip/hip_bf16.h>

// Problem constants: B=4, M=512, L=31, S=2, W=M+L-1=542
#define CB 4
#define CM 512
#define CL 31
#define CW 542
// Total output/H elements: B*M*M*L = 32,505,856 (divisible by 4)
#define TOTAL (CB * CM * CM * CL)

// X[b,m,n,l] = H[b,m,n,l] * (Y[b,m,n+l,0] + Y[b,m,n+l,1]); out = X / max(X)
// Flat H index f -> r = f/31 (= (b*M+m)*M + n), l = f%31.
// Y pair index = (r>>9)*542 + (r&511) + l   (M=512=2^9)

__device__ __forceinline__ float ygather(const float* __restrict__ Y, int r, int l) {
    int yi = ((r >> 9) * CW + (r & (CM - 1)) + l) * 2;
    float2 y = *(const float2*)(Y + yi);
    return y.x + y.y;
}

__global__ __launch_bounds__(256) void cassi_max(
    const float* __restrict__ Y,
    const float* __restrict__ H,
    int* __restrict__ gmax)
{
    int idx = blockIdx.x * 256 + threadIdx.x;
    float4 h = ((const float4*)H)[idx];
    int f = idx * 4;
    int r = f / CL;
    int l = f - r * CL;

    float mx;
    {
        float v0 = h.x * ygather(Y, r, l);
        ++l; if (l == CL) { l = 0; ++r; }
        float v1 = h.y * ygather(Y, r, l);
        ++l; if (l == CL) { l = 0; ++r; }
        float v2 = h.z * ygather(Y, r, l);
        ++l; if (l == CL) { l = 0; ++r; }
        float v3 = h.w * ygather(Y, r, l);
        mx = fmaxf(fmaxf(v0, v1), fmaxf(v2, v3));
    }

#pragma unroll
    for (int off = 32; off > 0; off >>= 1)
        mx = fmaxf(mx, __shfl_down(mx, off, 64));

    __shared__ float smax[4];
    int lane = threadIdx.x & 63;
    int wave = threadIdx.x >> 6;
    if (lane == 0) smax[wave] = mx;
    __syncthreads();
    if (threadIdx.x == 0) {
        float bmax = fmaxf(fmaxf(smax[0], smax[1]), fmaxf(smax[2], smax[3]));
        // All X >= 0 (H,Y uniform [0,1)), so int-compare == float-compare.
        atomicMax(gmax, __float_as_int(bmax));
    }
}

__global__ __launch_bounds__(256) void cassi_out(
    const float* __restrict__ Y,
    const float* __restrict__ H,
    const int* __restrict__ gmax,
    float* __restrict__ out)
{
    float inv = 1.0f / __int_as_float(*gmax);
    int idx = blockIdx.x * 256 + threadIdx.x;
    float4 h = ((const float4*)H)[idx];
    int f = idx * 4;
    int r = f / CL;
    int l = f - r * CL;

    float4 o;
    o.x = h.x * ygather(Y, r, l) * inv;
    ++l; if (l == CL) { l = 0; ++r; }
    o.y = h.y * ygather(Y, r, l) * inv;
    ++l; if (l == CL) { l = 0; ++r; }
    o.z = h.z * ygather(Y, r, l) * inv;
    ++l; if (l == CL) { l = 0; ++r; }
    o.w = h.w * ygather(Y, r, l) * inv;

    ((float4*)out)[idx] = o;
}

extern "C" void kernel_launch(void* const* d_in, const int* in_sizes, int n_in,
                              void* d_out, int out_size, void* d_ws, size_t ws_size,
                              hipStream_t stream)
{
    const float* Y = (const float*)d_in[0];   // (B, M, W, S)
    const float* H = (const float*)d_in[1];   // (B, M, M, L)
    float* out = (float*)d_out;               // (B, M, M, L) = 32,505,856 floats
    int* gmax = (int*)d_ws;

    hipMemsetAsync(d_ws, 0, sizeof(int), stream);  // 0.0f bits; X >= 0

    const int n4 = TOTAL / 4;                  // 8,126,464 float4
    const int blocks = n4 / 256;               // 31,744 exactly
    cassi_max<<<blocks, 256, 0, stream>>>(Y, H, gmax);
    cassi_out<<<blocks, 256, 0, stream>>>(Y, H, gmax, out);
}

// Round 3
// 268.829 us; speedup vs baseline: 2.1071x; 2.1071x over previous
//
#include <hip/hip_runtime.h>
#include <hip/hip_bf16.h>

// Problem constants: B=4, M=512, L=31, S=2, W=M+L-1=542
#define CB 4
#define CM 512
#define CL 31
#define CW 542
#define SLAB (CM * CL)          // 15872 floats of H per (b,m) slab
#define SLAB4 (SLAB / 4)        // 3968 float4
#define NBM (CB * CM)           // 2048 slabs

// X[b,m,n,l] = H[b,m,n,l] * (Y[b,m,n+l,0] + Y[b,m,n+l,1]); out = X / max(X)
// One block per (b,m) slab. Stage ysum[542] in LDS; H/out streamed as float4.

__device__ __forceinline__ void stage_ysum(const float* __restrict__ Y, int bm, float* ysum) {
    const float2* y2 = (const float2*)(Y + (size_t)bm * CW * 2);
    for (int j = threadIdx.x; j < CW; j += 256) {
        float2 v = y2[j];
        ysum[j] = v.x + v.y;
    }
    __syncthreads();
}

__global__ __launch_bounds__(256) void cassi_max(
    const float* __restrict__ Y,
    const float* __restrict__ H,
    int* __restrict__ gmax)
{
    __shared__ float ysum[CW];
    int bm = blockIdx.x;
    stage_ysum(Y, bm, ysum);

    const float4* h4 = (const float4*)(H + (size_t)bm * SLAB);

    float mx = 0.0f;   // all X >= 0
    for (int i = threadIdx.x; i < SLAB4; i += 256) {
        float4 h = h4[i];
        unsigned f = (unsigned)i * 4u;
        unsigned n0 = f / 31u,        l0 = f - n0 * 31u;
        unsigned n1 = (f + 1) / 31u,  l1 = (f + 1) - n1 * 31u;
        unsigned n2 = (f + 2) / 31u,  l2 = (f + 2) - n2 * 31u;
        unsigned n3 = (f + 3) / 31u,  l3 = (f + 3) - n3 * 31u;
        float v0 = h.x * ysum[n0 + l0];
        float v1 = h.y * ysum[n1 + l1];
        float v2 = h.z * ysum[n2 + l2];
        float v3 = h.w * ysum[n3 + l3];
        mx = fmaxf(mx, fmaxf(fmaxf(v0, v1), fmaxf(v2, v3)));
    }

#pragma unroll
    for (int off = 32; off > 0; off >>= 1)
        mx = fmaxf(mx, __shfl_down(mx, off, 64));

    __shared__ float smax[4];
    int lane = threadIdx.x & 63;
    int wave = threadIdx.x >> 6;
    if (lane == 0) smax[wave] = mx;
    __syncthreads();
    if (threadIdx.x == 0) {
        float bmax = fmaxf(fmaxf(smax[0], smax[1]), fmaxf(smax[2], smax[3]));
        // X >= 0 (H,Y uniform [0,1)), so int-compare == float-compare.
        atomicMax(gmax, __float_as_int(bmax));
    }
}

__global__ __launch_bounds__(256) void cassi_out(
    const float* __restrict__ Y,
    const float* __restrict__ H,
    const int* __restrict__ gmax,
    float* __restrict__ out)
{
    __shared__ float ysum[CW];
    int bm = blockIdx.x;
    stage_ysum(Y, bm, ysum);

    float inv = 1.0f / __int_as_float(*gmax);

    const float4* h4 = (const float4*)(H + (size_t)bm * SLAB);
    float4* o4 = (float4*)(out + (size_t)bm * SLAB);

    for (int i = threadIdx.x; i < SLAB4; i += 256) {
        float4 h = h4[i];
        unsigned f = (unsigned)i * 4u;
        unsigned n0 = f / 31u,        l0 = f - n0 * 31u;
        unsigned n1 = (f + 1) / 31u,  l1 = (f + 1) - n1 * 31u;
        unsigned n2 = (f + 2) / 31u,  l2 = (f + 2) - n2 * 31u;
        unsigned n3 = (f + 3) / 31u,  l3 = (f + 3) - n3 * 31u;
        float4 o;
        o.x = h.x * ysum[n0 + l0] * inv;
        o.y = h.y * ysum[n1 + l1] * inv;
        o.z = h.z * ysum[n2 + l2] * inv;
        o.w = h.w * ysum[n3 + l3] * inv;
        o4[i] = o;
    }
}

extern "C" void kernel_launch(void* const* d_in, const int* in_sizes, int n_in,
                              void* d_out, int out_size, void* d_ws, size_t ws_size,
                              hipStream_t stream)
{
    const float* Y = (const float*)d_in[0];   // (B, M, W, S)
    const float* H = (const float*)d_in[1];   // (B, M, M, L)
    float* out = (float*)d_out;               // (B, M, M, L)
    int* gmax = (int*)d_ws;

    hipMemsetAsync(d_ws, 0, sizeof(int), stream);  // 0.0f bits; X >= 0

    cassi_max<<<NBM, 256, 0, stream>>>(Y, H, gmax);
    cassi_out<<<NBM, 256, 0, stream>>>(Y, H, gmax, out);
}